// Round 4
// baseline (2596.450 us; speedup 1.0000x reference)
//
#include <hip/hip_runtime.h>
#include <cstdint>

#define DIMD 256
#define KCB  4096
#define NQ   4
#define NTOK 32768   // 8 * 4096

typedef __attribute__((ext_vector_type(8))) _Float16 half8;
typedef __attribute__((ext_vector_type(4))) _Float16 half4;
typedef __attribute__((ext_vector_type(4))) float f32x4;

// ---------------------------------------------------------------- helpers
__device__ __forceinline__ void async16(const void* g, void* l) {
  __builtin_amdgcn_global_load_lds(
      (const __attribute__((address_space(1))) unsigned int*)g,
      (__attribute__((address_space(3))) unsigned int*)l, 16, 0, 0);
}

__device__ __forceinline__ f32x4 mfma16(half8 a, half8 b, f32x4 c) {
  return __builtin_amdgcn_mfma_f32_16x16x32_f16(a, b, c, 0, 0, 0);
}

// ---------------------------------------------------------------- prep
// A plane frag-linear for mfma_f32_16x16x32 A-operand:
// half index = ((kc*(NTOK/16) + rowBlock16)*64 + (q*16 + (row&15)))*8 + j
// where element (row, d): kc=d>>5, q=(d>>3)&3, j=d&7.
__global__ void init_kernel(const float* __restrict__ x,
                            _Float16* __restrict__ At) {
  const int tid = threadIdx.x;
  const int n = blockIdx.x * 8 + (tid >> 5);
  const int t = tid & 31;
  const size_t base = (size_t)n * DIMD + t * 8;
  const float4 v0 = *(const float4*)&x[base];
  const float4 v1 = *(const float4*)&x[base + 4];
  const float f[8] = {v0.x, v0.y, v0.z, v0.w, v1.x, v1.y, v1.z, v1.w};
  half8 h;
  #pragma unroll
  for (int j = 0; j < 8; ++j) h[j] = (_Float16)f[j];
  const int kc = t >> 2, q = t & 3;
  *(half8*)&At[(((size_t)(kc * (NTOK / 16) + (n >> 4))) * 64 + q * 16 + (n & 15)) * 8] = h;
}

// B plane frag-linear, 64-col-chunk-major (one 64-col chunk = contiguous 32 KB):
// frag f = ((c>>6)*8 + kc)*4 + ((c>>4)&3); half = (f*64 + q*16 + (c&15))*8 + j.
// hcS[c] = 512 + 0.5*|cb_c|^2  (argmin key offset; d' = hcS - dot > 0 always).
__global__ void cb_prep_kernel(const float* __restrict__ cbs,
                               _Float16* __restrict__ Bt,
                               float* __restrict__ hcS) {
  const int tid = threadIdx.x;
  const int R = blockIdx.x * 8 + (tid >> 5);   // layer*4096 + code
  const int layer = R >> 12, c = R & 4095;
  const int t = tid & 31;
  const size_t base = (size_t)R * DIMD + t * 8;
  const float4 v0 = *(const float4*)&cbs[base];
  const float4 v1 = *(const float4*)&cbs[base + 4];
  const float f[8] = {v0.x, v0.y, v0.z, v0.w, v1.x, v1.y, v1.z, v1.w};
  half8 h;
  float s = 0.f;
  #pragma unroll
  for (int j = 0; j < 8; ++j) { h[j] = (_Float16)f[j]; s += f[j] * f[j]; }
  const int kc = t >> 2, q = t & 3;
  _Float16* BtL = Bt + (size_t)layer * KCB * DIMD;
  const int fr = ((c >> 6) * 8 + kc) * 4 + ((c >> 4) & 3);
  *(half8*)&BtL[((size_t)fr * 64 + q * 16 + (c & 15)) * 8] = h;
  #pragma unroll
  for (int off = 16; off > 0; off >>= 1) s += __shfl_down(s, off, 32);
  if (t == 0) hcS[R] = 512.0f + 0.5f * s;
}

// ---------------------------------------------------------------- argmin
// Occupancy-doubled layout: block = 4 waves = 256 rows x 512 cols (one
// EIGHTH of the codebook); grid = 128 rowgroups x 8 colE = 1024 blocks ->
// 4 blocks/CU (16 waves/CU). LDS = 2 x 16 KB double buffer + 2 KB hcs =
// 34 KB so 4 blocks fit; VGPR <= 128 so 4 waves/SIMD fit. The safe
// __syncthreads double-buffer is used: its vmcnt(0) drain is covered by
// the other 3 resident blocks' compute (the reason 2-block/CU variants of
// this kernel were latency-bound regardless of scheduling).
__device__ __forceinline__ void upd_keys(const f32x4 (&acc)[4], int tl,
                                         const float* __restrict__ hcs, int ln,
                                         uint32_t* __restrict__ u1,
                                         uint32_t* __restrict__ u2) {
  const float hcv = hcs[tl * 16 + ln];
  #pragma unroll
  for (int rt = 0; rt < 4; ++rt)
    #pragma unroll
    for (int reg = 0; reg < 4; ++reg) {
      const uint32_t k =
          (__float_as_uint(hcv - acc[rt][reg]) & 0xFFFFFFC0u) | (uint32_t)tl;
      const int s = rt * 4 + reg;
      const uint32_t mx = u1[s] > k ? u1[s] : k;
      u1[s] = u1[s] < k ? u1[s] : k;
      u2[s] = u2[s] < mx ? u2[s] : mx;
    }
}

// 32-col chunk LDS layout: frag L = kc*2 + tsub (1 KB each); b for (kc,tsub)
// at halves offset (kc*2+tsub)*512 + lane*8, i.e. kc stride 1024 halves.
// b loaded in two batches of 4 (16 live VGPRs) to keep the allocator <=128.
template <bool DO_PREV>
__device__ __forceinline__ void tile_pp(f32x4 (&acc)[4], const f32x4 (&pacc)[4],
                                        const half8 (&a)[4][8],
                                        const _Float16* __restrict__ bs,
                                        int tsub, int tl,
                                        const float* __restrict__ hcs,
                                        int ln, int lane,
                                        uint32_t* __restrict__ u1,
                                        uint32_t* __restrict__ u2) {
  const _Float16* bp = bs + tsub * 512 + lane * 8;
  const half8 b0 = *(const half8*)(bp);
  const half8 b1 = *(const half8*)(bp + 1024);
  const half8 b2 = *(const half8*)(bp + 2048);
  const half8 b3 = *(const half8*)(bp + 3072);
  if constexpr (DO_PREV) upd_keys(pacc, tl - 1, hcs, ln, u1, u2);
  const f32x4 z = {0.f, 0.f, 0.f, 0.f};
  __builtin_amdgcn_s_setprio(1);
  acc[0] = mfma16(a[0][0], b0, z);
  acc[1] = mfma16(a[1][0], b0, z);
  acc[2] = mfma16(a[2][0], b0, z);
  acc[3] = mfma16(a[3][0], b0, z);
  #pragma unroll
  for (int rt = 0; rt < 4; ++rt) acc[rt] = mfma16(a[rt][1], b1, acc[rt]);
  #pragma unroll
  for (int rt = 0; rt < 4; ++rt) acc[rt] = mfma16(a[rt][2], b2, acc[rt]);
  #pragma unroll
  for (int rt = 0; rt < 4; ++rt) acc[rt] = mfma16(a[rt][3], b3, acc[rt]);
  const half8 b4 = *(const half8*)(bp + 4096);
  const half8 b5 = *(const half8*)(bp + 5120);
  const half8 b6 = *(const half8*)(bp + 6144);
  const half8 b7 = *(const half8*)(bp + 7168);
  #pragma unroll
  for (int rt = 0; rt < 4; ++rt) acc[rt] = mfma16(a[rt][4], b4, acc[rt]);
  #pragma unroll
  for (int rt = 0; rt < 4; ++rt) acc[rt] = mfma16(a[rt][5], b5, acc[rt]);
  #pragma unroll
  for (int rt = 0; rt < 4; ++rt) acc[rt] = mfma16(a[rt][6], b6, acc[rt]);
  #pragma unroll
  for (int rt = 0; rt < 4; ++rt) acc[rt] = mfma16(a[rt][7], b7, acc[rt]);
  __builtin_amdgcn_s_setprio(0);
}

// One 32-col chunk = 2 tiles (tl = 2c, 2c+1). acc alternates A,B; keys
// consume the opposite buffer (previous tile). On exit accB holds tl=2c+1.
template <bool FIRST>
__device__ __forceinline__ void chunk32(int c, const _Float16* __restrict__ bs,
                                        const half8 (&a)[4][8],
                                        f32x4 (&accA)[4], f32x4 (&accB)[4],
                                        const float* __restrict__ hcs,
                                        int ln, int lane,
                                        uint32_t* __restrict__ u1,
                                        uint32_t* __restrict__ u2) {
  tile_pp<!FIRST>(accA, accB, a, bs, 0, 2 * c, hcs, ln, lane, u1, u2);
  tile_pp<true >(accB, accA, a, bs, 1, 2 * c + 1, hcs, ln, lane, u1, u2);
}

// stage one 32-col chunk (16 frags of 1 KB); wave w stages frags w*4..w*4+3.
// source frag within the 64-col cb_prep chunk: g = kc*4 + (c&1)*2 + s.
__device__ __forceinline__ void stage32(const char* __restrict__ BtE, int c,
                                        int w, int lane, void* buf) {
  #pragma unroll
  for (int i = 0; i < 4; ++i) {
    const int kc = w * 2 + (i >> 1), s = i & 1;
    async16(BtE + (size_t)(c >> 1) * 32768 +
                (size_t)(kc * 4 + (c & 1) * 2 + s) * 1024 + lane * 16,
            (char*)buf + (w * 4 + i) * 1024 + lane * 16);
  }
}

__global__ __launch_bounds__(256, 4) void argmin_kernel(
    const _Float16* __restrict__ At,
    const _Float16* __restrict__ Bt,     // layer base (chunk-major frag-linear)
    const float* __restrict__ hcS,       // layer base
    uint2* __restrict__ part)            // [NTOK][8] best-2 col indices
{
  __shared__ _Float16 Bs[2][8192];       // 2 x 16 KB (32-col chunks)
  __shared__ float hcs[512];

  const int tid = threadIdx.x;
  const int lane = tid & 63, w = tid >> 6;   // 4 waves
  const int rg   = blockIdx.x & 127;         // stride-128 siblings share rows
  const int colE = blockIdx.x >> 7;          // eighth of the codebook
  const int quad = lane >> 4, ln = lane & 15;

  const char* BtE = (const char*)Bt + (size_t)colE * 262144;

  // prefetch chunk 0
  stage32(BtE, 0, w, lane, &Bs[0][0]);

  // stage hcS eighth to LDS (512 floats)
  *(float2*)&hcs[tid * 2] = *(const float2*)&hcS[colE * 512 + tid * 2];

  // upfront A: 64 rows x 256 d in registers (32 x dwordx4)
  const int rb16 = rg * 16 + w * 4;
  half8 a[4][8];
  #pragma unroll
  for (int kc = 0; kc < 8; ++kc)
    #pragma unroll
    for (int rt = 0; rt < 4; ++rt)
      a[rt][kc] = *(const half8*)&At[(((size_t)(kc * (NTOK / 16) + rb16 + rt)) * 64 + lane) * 8];

  // best-2 keys per element (16 rows/lane): key = trunc6(as_uint(d')) | tile
  uint32_t u1[16], u2[16];
  #pragma unroll
  for (int s = 0; s < 16; ++s) { u1[s] = 0xFFFFFFFFu; u2[s] = 0xFFFFFFFFu; }

  f32x4 accA[4], accB[4];

  __syncthreads();

  // ---- chunk 0 (peeled: no prev-tile keys at the first tile)
  stage32(BtE, 1, w, lane, &Bs[1][0]);
  chunk32<true>(0, &Bs[0][0], a, accA, accB, hcs, ln, lane, u1, u2);
  __syncthreads();

  // ---- steady state c = 1..14
  for (int c = 1; c < 15; ++c) {
    stage32(BtE, c + 1, w, lane, &Bs[(c + 1) & 1][0]);
    chunk32<false>(c, &Bs[c & 1][0], a, accA, accB, hcs, ln, lane, u1, u2);
    __syncthreads();
  }

  // ---- chunk 15 (peeled: nothing left to stage)
  chunk32<false>(15, &Bs[1][0], a, accA, accB, hcs, ln, lane, u1, u2);

  // tile 31 keys (accB) from the epilogue
  upd_keys(accB, 31, hcs, ln, u1, u2);

  // flush: reconstruct cols, merge best-2 across the 16 ln lanes, write part
  #pragma unroll
  for (int s = 0; s < 16; ++s) {
    uint32_t k1 = u1[s], k2 = u2[s];
    int c1 = colE * 512 + (int)(k1 & 63u) * 16 + ln;
    int c2 = colE * 512 + (int)(k2 & 63u) * 16 + ln;
    #pragma unroll
    for (int m = 1; m <= 8; m <<= 1) {
      const uint32_t o1 = (uint32_t)__shfl_xor((int)k1, m, 64);
      const int      oc1 = __shfl_xor(c1, m, 64);
      const uint32_t o2 = (uint32_t)__shfl_xor((int)k2, m, 64);
      const int      oc2 = __shfl_xor(c2, m, 64);
      const bool t1 = k1 <= o1;
      const uint32_t am = t1 ? o1 : k1; const int amc = t1 ? oc1 : c1;
      k1 = t1 ? k1 : o1;                c1 = t1 ? c1 : oc1;
      const bool t2 = k2 <= o2;
      const uint32_t bm = t2 ? k2 : o2; const int bmc = t2 ? c2 : oc2;
      const bool t3 = am <= bm;
      k2 = t3 ? am : bm;                c2 = t3 ? amc : bmc;
    }
    if (ln == 0) {
      const int rt = s >> 2, reg = s & 3;
      const int row = rg * 256 + w * 64 + rt * 16 + quad * 4 + reg;
      part[(size_t)row * 8 + colE] = make_uint2((uint32_t)c1, (uint32_t)c2);
    }
  }
}

// ------------------------- fused fp64 rescore (16 cands) + STE update + loss
// Residual identity: res_final = x - sum(stv) exactly, so `out` is written
// only at the last layer as out = x - nr (fp diff vs ref sum order ~2e-6).
__global__ void post_kernel(const uint2* __restrict__ part,
                            const float* __restrict__ rsrc,  // x (q=0) or res
                            float* __restrict__ rdst,        // res
                            const float* __restrict__ xin,   // x (last layer)
                            const float* __restrict__ cb,    // layer fp32
                            float* __restrict__ out,
                            _Float16* __restrict__ At,
                            float* __restrict__ idxf,
                            float* __restrict__ lossP,       // 256 slots
                            int writeRes, int emit, int writeOut) {
  __shared__ float ls[4];
  const int lane = threadIdx.x & 63;
  const int rsub = threadIdx.x >> 6;
  const int row = blockIdx.x * 4 + rsub;

  // lane-parallel rescore over 16 candidates: cand id = lane>>2 (direct
  // per-lane load, no runtime-indexed local array), dim group = (lane&3)*64
  const int cd = lane >> 2, dg = lane & 3;
  const int myc = (int)((const uint32_t*)part)[(size_t)row * 16 + cd];
  const float* rrow = rsrc + (size_t)row * DIMD;
  const float* qrow = cb + (size_t)myc * DIMD;
  double d = 0.0;
  #pragma unroll
  for (int k = 0; k < 16; ++k) {
    const int dd = dg * 64 + k * 4;
    const float4 rv = *(const float4*)&rrow[dd];
    const float4 qv = *(const float4*)&qrow[dd];
    const double t0 = (double)rv.x - (double)qv.x;
    const double t1 = (double)rv.y - (double)qv.y;
    const double t2 = (double)rv.z - (double)qv.z;
    const double t3 = (double)rv.w - (double)qv.w;
    d += t0 * t0 + t1 * t1 + t2 * t2 + t3 * t3;
  }
  d += __shfl_xor(d, 1, 64);
  d += __shfl_xor(d, 2, 64);
  double bd = d; int bc = myc;
  #pragma unroll
  for (int m = 4; m <= 32; m <<= 1) {
    const double od = __shfl_xor(bd, m, 64);
    const int    oc = __shfl_xor(bc, m, 64);
    if (od < bd || (od == bd && oc < bc)) { bd = od; bc = oc; }
  }
  const int win = bc;

  // STE update (reference rounding)
  const size_t base = (size_t)row * DIMD + lane * 4;
  const float4 r4 = *(const float4*)&rsrc[base];
  const float4 q4 = *(const float4*)&cb[(size_t)win * DIMD + lane * 4];
  const float rr[4] = {r4.x, r4.y, r4.z, r4.w};
  const float qq[4] = {q4.x, q4.y, q4.z, q4.w};
  float nr[4];
  float s2 = 0.f;
  #pragma unroll
  for (int j = 0; j < 4; ++j) {
    const float stv = rr[j] + (qq[j] - rr[j]);
    nr[j] = rr[j] - stv;
    const float dl = rr[j] - qq[j];
    s2 += dl * dl;
  }
  if (writeRes)
    *(float4*)&rdst[base] = make_float4(nr[0], nr[1], nr[2], nr[3]);
  if (writeOut) {
    const float4 xv = *(const float4*)&xin[base];
    *(float4*)&out[base] =
        make_float4(xv.x - nr[0], xv.y - nr[1], xv.z - nr[2], xv.w - nr[3]);
  }
  if (emit) {
    half4 h;
    #pragma unroll
    for (int j = 0; j < 4; ++j) h[j] = (_Float16)nr[j];
    const int kc = lane >> 3, q = (lane >> 1) & 3, jo = (lane & 1) * 4;
    *(half4*)&At[(((size_t)(kc * (NTOK / 16) + (row >> 4))) * 64 + q * 16 + (row & 15)) * 8 + jo] = h;
  }
  if (lane == 0) idxf[row] = (float)win;

  #pragma unroll
  for (int m = 1; m < 64; m <<= 1) s2 += __shfl_xor(s2, m, 64);
  if (lane == 0) ls[rsub] = s2;
  __syncthreads();
  if (threadIdx.x == 0) {
    const float tot = ls[0] + ls[1] + ls[2] + ls[3];
    atomicAdd(&lossP[blockIdx.x & 255],
              tot * (1.0f / (float)((size_t)NTOK * DIMD)));
  }
}

// sum 4 x 256 loss partials -> losses[4]
__global__ void finalize_kernel(const float* __restrict__ lossP,
                                float* __restrict__ losses) {
  const int w = threadIdx.x >> 6, lane = threadIdx.x & 63;
  float s = lossP[w * 256 + lane] + lossP[w * 256 + 64 + lane] +
            lossP[w * 256 + 128 + lane] + lossP[w * 256 + 192 + lane];
  #pragma unroll
  for (int m = 1; m < 64; m <<= 1) s += __shfl_xor(s, m, 64);
  if (lane == 0) losses[w] = s;
}

// ---------------------------------------------------------------- launch
extern "C" void kernel_launch(void* const* d_in, const int* in_sizes, int n_in,
                              void* d_out, int out_size, void* d_ws, size_t ws_size,
                              hipStream_t stream) {
  const float* x   = (const float*)d_in[0];   // [8,4096,256]
  const float* cbs = (const float*)d_in[1];   // [4,4096,256]

  float* out    = (float*)d_out;
  float* idxf   = out + (size_t)NTOK * DIMD;
  float* losses = idxf + (size_t)NQ * NTOK;

  char* wsp = (char*)d_ws;
  float* res = (float*)wsp;                    wsp += (size_t)NTOK * DIMD * 4;      // 32 MB
  _Float16* At = (_Float16*)wsp;               wsp += (size_t)NTOK * DIMD * 2;      // 16 MB
  _Float16* Bt = (_Float16*)wsp;               wsp += (size_t)NQ * KCB * DIMD * 2;  //  8 MB
  float* hcS = (float*)wsp;                    wsp += (size_t)NQ * KCB * 4;
  uint2* part = (uint2*)wsp;                   wsp += (size_t)NTOK * 8 * 8;         //  2 MB
  float* lossP = (float*)wsp;                  wsp += (size_t)NQ * 256 * 4;

  hipMemsetAsync(lossP, 0, NQ * 256 * sizeof(float), stream);
  cb_prep_kernel<<<NQ * KCB / 8, 256, 0, stream>>>(cbs, Bt, hcS);
  init_kernel<<<NTOK / 8, 256, 0, stream>>>(x, At);

  for (int q = 0; q < NQ; ++q) {
    const float* cb = cbs + (size_t)q * KCB * DIMD;
    argmin_kernel<<<1024, 256, 0, stream>>>(At, Bt + (size_t)q * KCB * DIMD,
                                            hcS + (size_t)q * KCB, part);
    const int last = (q == NQ - 1);
    post_kernel<<<NTOK / 4, 256, 0, stream>>>(
        part, q == 0 ? x : res, res, x, cb, out, At,
        idxf + (size_t)q * NTOK, lossP + (size_t)q * 256,
        /*writeRes=*/!last, /*emit=*/!last, /*writeOut=*/last);
  }
  finalize_kernel<<<1, 256, 0, stream>>>(lossP, losses);
}

// Round 5
// 623.191 us; speedup vs baseline: 4.1664x; 4.1664x over previous
//
#include <hip/hip_runtime.h>
#include <cstdint>

#define DIMD 256
#define KCB  4096
#define NQ   4
#define NTOK 32768   // 8 * 4096

typedef __attribute__((ext_vector_type(8))) _Float16 half8;
typedef __attribute__((ext_vector_type(4))) _Float16 half4;
typedef __attribute__((ext_vector_type(4))) float f32x4;

// ---------------------------------------------------------------- helpers
__device__ __forceinline__ f32x4 mfma16(half8 a, half8 b, f32x4 c) {
  return __builtin_amdgcn_mfma_f32_16x16x32_f16(a, b, c, 0, 0, 0);
}

// ---------------------------------------------------------------- prep
// A plane frag-linear for mfma_f32_16x16x32 A-operand:
// half index = ((kc*(NTOK/16) + rowBlock16)*64 + (q*16 + (row&15)))*8 + j
// where element (row, d): kc=d>>5, q=(d>>3)&3, j=d&7.
__global__ void init_kernel(const float* __restrict__ x,
                            _Float16* __restrict__ At) {
  const int tid = threadIdx.x;
  const int n = blockIdx.x * 8 + (tid >> 5);
  const int t = tid & 31;
  const size_t base = (size_t)n * DIMD + t * 8;
  const float4 v0 = *(const float4*)&x[base];
  const float4 v1 = *(const float4*)&x[base + 4];
  const float f[8] = {v0.x, v0.y, v0.z, v0.w, v1.x, v1.y, v1.z, v1.w};
  half8 h;
  #pragma unroll
  for (int j = 0; j < 8; ++j) h[j] = (_Float16)f[j];
  const int kc = t >> 2, q = t & 3;
  *(half8*)&At[(((size_t)(kc * (NTOK / 16) + (n >> 4))) * 64 + q * 16 + (n & 15)) * 8] = h;
}

// B plane frag-linear, 64-col-chunk-major (one 64-col chunk = contiguous 32 KB):
// frag f = ((c>>6)*8 + kc)*4 + ((c>>4)&3); half = (f*64 + q*16 + (c&15))*8 + j.
// hcS[c] = 512 + 0.5*|cb_c|^2  (argmin key offset; d' = hcS - dot > 0 always).
__global__ void cb_prep_kernel(const float* __restrict__ cbs,
                               _Float16* __restrict__ Bt,
                               float* __restrict__ hcS) {
  const int tid = threadIdx.x;
  const int R = blockIdx.x * 8 + (tid >> 5);   // layer*4096 + code
  const int layer = R >> 12, c = R & 4095;
  const int t = tid & 31;
  const size_t base = (size_t)R * DIMD + t * 8;
  const float4 v0 = *(const float4*)&cbs[base];
  const float4 v1 = *(const float4*)&cbs[base + 4];
  const float f[8] = {v0.x, v0.y, v0.z, v0.w, v1.x, v1.y, v1.z, v1.w};
  half8 h;
  float s = 0.f;
  #pragma unroll
  for (int j = 0; j < 8; ++j) { h[j] = (_Float16)f[j]; s += f[j] * f[j]; }
  const int kc = t >> 2, q = t & 3;
  _Float16* BtL = Bt + (size_t)layer * KCB * DIMD;
  const int fr = ((c >> 6) * 8 + kc) * 4 + ((c >> 4) & 3);
  *(half8*)&BtL[((size_t)fr * 64 + q * 16 + (c & 15)) * 8] = h;
  #pragma unroll
  for (int off = 16; off > 0; off >>= 1) s += __shfl_down(s, off, 32);
  if (t == 0) hcS[R] = 512.0f + 0.5f * s;
}

// ---------------------------------------------------------------- argmin
// A resident in registers (64 rows x 256 d per wave, read once); B streamed
// DIRECTLY from L2 into registers (no LDS staging, no barriers in the main
// loop). B has zero intra-wave reuse, and a whole layer's B (2 MB) fits each
// XCD's 4 MB L2, so LDS staging bought only phase-locking overhead: the
// per-chunk __syncthreads (full vmcnt/lgkm drain) was ~55% of the wall at
// 2 waves/SIMD. Now each wave free-runs over its 64 tiles with a p/q
// half-tile register pipeline (loads issued one compute-phase ahead, ~310
// cyc cover vs ~250 cyc L2 latency); the 2 waves/SIMD anti-phase naturally
// and setprio arbitrates the matrix pipe.
__device__ __forceinline__ void upd_keys(const f32x4 (&acc)[4], int tl,
                                         const float* __restrict__ hcs, int ln,
                                         uint32_t* __restrict__ u1,
                                         uint32_t* __restrict__ u2) {
  const float hcv = hcs[tl * 16 + ln];
  #pragma unroll
  for (int rt = 0; rt < 4; ++rt)
    #pragma unroll
    for (int reg = 0; reg < 4; ++reg) {
      const uint32_t k =
          (__float_as_uint(hcv - acc[rt][reg]) & 0xFFFFFFC0u) | (uint32_t)tl;
      const int s = rt * 4 + reg;
      const uint32_t mx = u1[s] > k ? u1[s] : k;
      u1[s] = u1[s] < k ? u1[s] : k;
      u2[s] = u2[s] < mx ? u2[s] : mx;
    }
}

__global__ __launch_bounds__(256, 2) void argmin_kernel(
    const _Float16* __restrict__ At,
    const _Float16* __restrict__ Bt,     // layer base (chunk-major frag-linear)
    const float* __restrict__ hcS,       // layer base
    uint2* __restrict__ part)            // [NTOK][4] best-2 col indices
{
  __shared__ float hcs[1024];

  const int tid = threadIdx.x;
  const int lane = tid & 63, w = tid >> 6;   // 4 waves
  const int rg   = blockIdx.x & 127;         // stride-128 siblings share rows
  const int colQ = blockIdx.x >> 7;
  const int quad = lane >> 4, ln = lane & 15;

  // stage hcS quarter to LDS (1024 floats)
  *(float4*)&hcs[tid * 4] = *(const float4*)&hcS[colQ * 1024 + tid * 4];

  // upfront A: 64 rows x 256 d in registers (32 x dwordx4)
  const int rb16 = rg * 16 + w * 4;
  half8 a[4][8];
  #pragma unroll
  for (int kc = 0; kc < 8; ++kc)
    #pragma unroll
    for (int rt = 0; rt < 4; ++rt)
      a[rt][kc] = *(const half8*)&At[(((size_t)(kc * (NTOK / 16) + rb16 + rt)) * 64 + lane) * 8];

  // best-2 keys per element (16 rows/lane): key = trunc6(as_uint(d')) | tile
  uint32_t u1[16], u2[16];
  #pragma unroll
  for (int s = 0; s < 16; ++s) { u1[s] = 0xFFFFFFFFu; u2[s] = 0xFFFFFFFFu; }

  // quarter base: colQ*1024 cols * 256 d = colQ * 262144 halves
  const _Float16* Bq = Bt + (size_t)colQ * 262144 + lane * 8;
  // frag address for (tile t, kc): ((t>>2)*8 + kc)*4 + (t&3), 512 halves each
  #define BFRAG(t, kc) \
    (*(const half8*)&Bq[(size_t)((((t) >> 2) * 8 + (kc)) * 4 + ((t) & 3)) * 512])

  half8 p[4], q[4];
  #pragma unroll
  for (int k = 0; k < 4; ++k) p[k] = BFRAG(0, k);
  #pragma unroll
  for (int k = 0; k < 4; ++k) q[k] = BFRAG(0, 4 + k);

  __syncthreads();   // hcs ready (only barrier in the kernel)

  f32x4 acc[4];
  const f32x4 z = {0.f, 0.f, 0.f, 0.f};

  for (int t = 0; t < 64; ++t) {
    const int tn = (t + 1) & 63;   // wrap keeps addresses valid; t=63 reload is dead
    __builtin_amdgcn_s_setprio(1);
    // consume p (kc 0..3)
    acc[0] = mfma16(a[0][0], p[0], z);
    acc[1] = mfma16(a[1][0], p[0], z);
    acc[2] = mfma16(a[2][0], p[0], z);
    acc[3] = mfma16(a[3][0], p[0], z);
    #pragma unroll
    for (int rt = 0; rt < 4; ++rt) acc[rt] = mfma16(a[rt][1], p[1], acc[rt]);
    #pragma unroll
    for (int rt = 0; rt < 4; ++rt) acc[rt] = mfma16(a[rt][2], p[2], acc[rt]);
    #pragma unroll
    for (int rt = 0; rt < 4; ++rt) acc[rt] = mfma16(a[rt][3], p[3], acc[rt]);
    __builtin_amdgcn_s_setprio(0);
    // refill p <- tile tn half 0 (covered by q-consume + keys)
    #pragma unroll
    for (int k = 0; k < 4; ++k) p[k] = BFRAG(tn, k);
    __builtin_amdgcn_s_setprio(1);
    // consume q (kc 4..7)
    #pragma unroll
    for (int rt = 0; rt < 4; ++rt) acc[rt] = mfma16(a[rt][4], q[0], acc[rt]);
    #pragma unroll
    for (int rt = 0; rt < 4; ++rt) acc[rt] = mfma16(a[rt][5], q[1], acc[rt]);
    #pragma unroll
    for (int rt = 0; rt < 4; ++rt) acc[rt] = mfma16(a[rt][6], q[2], acc[rt]);
    #pragma unroll
    for (int rt = 0; rt < 4; ++rt) acc[rt] = mfma16(a[rt][7], q[3], acc[rt]);
    __builtin_amdgcn_s_setprio(0);
    // refill q <- tile tn half 1 (covered by keys + next p-consume)
    #pragma unroll
    for (int k = 0; k < 4; ++k) q[k] = BFRAG(tn, 4 + k);
    // best-2 key update for tile t
    upd_keys(acc, t, hcs, ln, u1, u2);
  }
  #undef BFRAG

  // flush: reconstruct cols, merge best-2 across the 16 ln lanes, write part
  #pragma unroll
  for (int s = 0; s < 16; ++s) {
    uint32_t k1 = u1[s], k2 = u2[s];
    int c1 = colQ * 1024 + (int)(k1 & 63u) * 16 + ln;
    int c2 = colQ * 1024 + (int)(k2 & 63u) * 16 + ln;
    #pragma unroll
    for (int m = 1; m <= 8; m <<= 1) {
      const uint32_t o1 = (uint32_t)__shfl_xor((int)k1, m, 64);
      const int      oc1 = __shfl_xor(c1, m, 64);
      const uint32_t o2 = (uint32_t)__shfl_xor((int)k2, m, 64);
      const int      oc2 = __shfl_xor(c2, m, 64);
      const bool t1 = k1 <= o1;
      const uint32_t am = t1 ? o1 : k1; const int amc = t1 ? oc1 : c1;
      k1 = t1 ? k1 : o1;                c1 = t1 ? c1 : oc1;
      const bool t2 = k2 <= o2;
      const uint32_t bm = t2 ? k2 : o2; const int bmc = t2 ? c2 : oc2;
      const bool t3 = am <= bm;
      k2 = t3 ? am : bm;                c2 = t3 ? amc : bmc;
    }
    if (ln == 0) {
      const int rt = s >> 2, reg = s & 3;
      const int row = rg * 256 + w * 64 + rt * 16 + quad * 4 + reg;
      part[(size_t)row * 4 + colQ] = make_uint2((uint32_t)c1, (uint32_t)c2);
    }
  }
}

// ------------------------- fused fp64 rescore (8 cands) + STE update + loss
// Residual identity: res_final = x - sum(stv) exactly, so `out` is written
// only at the last layer as out = x - nr (fp diff vs ref sum order ~2e-6).
__global__ void post_kernel(const uint2* __restrict__ part,
                            const float* __restrict__ rsrc,  // x (q=0) or res
                            float* __restrict__ rdst,        // res
                            const float* __restrict__ xin,   // x (last layer)
                            const float* __restrict__ cb,    // layer fp32
                            float* __restrict__ out,
                            _Float16* __restrict__ At,
                            float* __restrict__ idxf,
                            float* __restrict__ lossP,       // 256 slots
                            int writeRes, int emit, int writeOut) {
  __shared__ float ls[4];
  const int lane = threadIdx.x & 63;
  const int rsub = threadIdx.x >> 6;
  const int row = blockIdx.x * 4 + rsub;

  // lane-parallel rescore: cand id = lane>>3 (direct per-lane load, no
  // runtime-indexed local array), dim group = (lane&7)*32
  const int cd = lane >> 3, dg = lane & 7;
  const int myc = (int)((const uint32_t*)part)[(size_t)row * 8 + cd];
  const float* rrow = rsrc + (size_t)row * DIMD;
  const float* qrow = cb + (size_t)myc * DIMD;
  double d = 0.0;
  #pragma unroll
  for (int k = 0; k < 8; ++k) {
    const int dd = dg * 32 + k * 4;
    const float4 rv = *(const float4*)&rrow[dd];
    const float4 qv = *(const float4*)&qrow[dd];
    const double t0 = (double)rv.x - (double)qv.x;
    const double t1 = (double)rv.y - (double)qv.y;
    const double t2 = (double)rv.z - (double)qv.z;
    const double t3 = (double)rv.w - (double)qv.w;
    d += t0 * t0 + t1 * t1 + t2 * t2 + t3 * t3;
  }
  #pragma unroll
  for (int m = 1; m <= 4; m <<= 1) d += __shfl_xor(d, m, 64);
  double bd = d; int bc = myc;
  #pragma unroll
  for (int m = 8; m <= 32; m <<= 1) {
    const double od = __shfl_xor(bd, m, 64);
    const int    oc = __shfl_xor(bc, m, 64);
    if (od < bd || (od == bd && oc < bc)) { bd = od; bc = oc; }
  }
  const int win = bc;

  // STE update (reference rounding)
  const size_t base = (size_t)row * DIMD + lane * 4;
  const float4 r4 = *(const float4*)&rsrc[base];
  const float4 q4 = *(const float4*)&cb[(size_t)win * DIMD + lane * 4];
  const float rr[4] = {r4.x, r4.y, r4.z, r4.w};
  const float qq[4] = {q4.x, q4.y, q4.z, q4.w};
  float nr[4];
  float s2 = 0.f;
  #pragma unroll
  for (int j = 0; j < 4; ++j) {
    const float stv = rr[j] + (qq[j] - rr[j]);
    nr[j] = rr[j] - stv;
    const float dl = rr[j] - qq[j];
    s2 += dl * dl;
  }
  if (writeRes)
    *(float4*)&rdst[base] = make_float4(nr[0], nr[1], nr[2], nr[3]);
  if (writeOut) {
    const float4 xv = *(const float4*)&xin[base];
    *(float4*)&out[base] =
        make_float4(xv.x - nr[0], xv.y - nr[1], xv.z - nr[2], xv.w - nr[3]);
  }
  if (emit) {
    half4 h;
    #pragma unroll
    for (int j = 0; j < 4; ++j) h[j] = (_Float16)nr[j];
    const int kc = lane >> 3, q = (lane >> 1) & 3, jo = (lane & 1) * 4;
    *(half4*)&At[(((size_t)(kc * (NTOK / 16) + (row >> 4))) * 64 + q * 16 + (row & 15)) * 8 + jo] = h;
  }
  if (lane == 0) idxf[row] = (float)win;

  #pragma unroll
  for (int m = 1; m < 64; m <<= 1) s2 += __shfl_xor(s2, m, 64);
  if (lane == 0) ls[rsub] = s2;
  __syncthreads();
  if (threadIdx.x == 0) {
    const float tot = ls[0] + ls[1] + ls[2] + ls[3];
    atomicAdd(&lossP[blockIdx.x & 255],
              tot * (1.0f / (float)((size_t)NTOK * DIMD)));
  }
}

// sum 4 x 256 loss partials -> losses[4]
__global__ void finalize_kernel(const float* __restrict__ lossP,
                                float* __restrict__ losses) {
  const int w = threadIdx.x >> 6, lane = threadIdx.x & 63;
  float s = lossP[w * 256 + lane] + lossP[w * 256 + 64 + lane] +
            lossP[w * 256 + 128 + lane] + lossP[w * 256 + 192 + lane];
  #pragma unroll
  for (int m = 1; m < 64; m <<= 1) s += __shfl_xor(s, m, 64);
  if (lane == 0) losses[w] = s;
}

// ---------------------------------------------------------------- launch
extern "C" void kernel_launch(void* const* d_in, const int* in_sizes, int n_in,
                              void* d_out, int out_size, void* d_ws, size_t ws_size,
                              hipStream_t stream) {
  const float* x   = (const float*)d_in[0];   // [8,4096,256]
  const float* cbs = (const float*)d_in[1];   // [4,4096,256]

  float* out    = (float*)d_out;
  float* idxf   = out + (size_t)NTOK * DIMD;
  float* losses = idxf + (size_t)NQ * NTOK;

  char* wsp = (char*)d_ws;
  float* res = (float*)wsp;                    wsp += (size_t)NTOK * DIMD * 4;      // 32 MB
  _Float16* At = (_Float16*)wsp;               wsp += (size_t)NTOK * DIMD * 2;      // 16 MB
  _Float16* Bt = (_Float16*)wsp;               wsp += (size_t)NQ * KCB * DIMD * 2;  //  8 MB
  float* hcS = (float*)wsp;                    wsp += (size_t)NQ * KCB * 4;
  uint2* part = (uint2*)wsp;                   wsp += (size_t)NTOK * 4 * 8;
  float* lossP = (float*)wsp;                  wsp += (size_t)NQ * 256 * 4;

  hipMemsetAsync(lossP, 0, NQ * 256 * sizeof(float), stream);
  cb_prep_kernel<<<NQ * KCB / 8, 256, 0, stream>>>(cbs, Bt, hcS);
  init_kernel<<<NTOK / 8, 256, 0, stream>>>(x, At);

  for (int q = 0; q < NQ; ++q) {
    const float* cb = cbs + (size_t)q * KCB * DIMD;
    argmin_kernel<<<512, 256, 0, stream>>>(At, Bt + (size_t)q * KCB * DIMD,
                                           hcS + (size_t)q * KCB, part);
    const int last = (q == NQ - 1);
    post_kernel<<<NTOK / 4, 256, 0, stream>>>(
        part, q == 0 ? x : res, res, x, cb, out, At,
        idxf + (size_t)q * NTOK, lossP + (size_t)q * 256,
        /*writeRes=*/!last, /*emit=*/!last, /*writeOut=*/last);
  }
  finalize_kernel<<<1, 256, 0, stream>>>(lossP, losses);
}

// Round 6
// 495.658 us; speedup vs baseline: 5.2384x; 1.2573x over previous
//
#include <hip/hip_runtime.h>
#include <cstdint>

#define DIMD 256
#define KCB  4096
#define NQ   4
#define NTOK 32768   // 8 * 4096

typedef __attribute__((ext_vector_type(8))) _Float16 half8;
typedef __attribute__((ext_vector_type(4))) _Float16 half4;
typedef __attribute__((ext_vector_type(4))) float f32x4;

// ---------------------------------------------------------------- helpers
__device__ __forceinline__ f32x4 mfma16(half8 a, half8 b, f32x4 c) {
  return __builtin_amdgcn_mfma_f32_16x16x32_f16(a, b, c, 0, 0, 0);
}

// ---------------------------------------------------------------- prep
// At is ROW-MAJOR fp16 [NTOK][256]: init and post's emit are fully
// coalesced; argmin does the MFMA fragment gather on its once-per-kernel
// A-load (amortized over 64 tiles).
__global__ void init_kernel(const float* __restrict__ x,
                            _Float16* __restrict__ At) {
  const int tid = threadIdx.x;
  const int n = blockIdx.x * 8 + (tid >> 5);
  const int t = tid & 31;
  const size_t base = (size_t)n * DIMD + t * 8;
  const float4 v0 = *(const float4*)&x[base];
  const float4 v1 = *(const float4*)&x[base + 4];
  const float f[8] = {v0.x, v0.y, v0.z, v0.w, v1.x, v1.y, v1.z, v1.w};
  half8 h;
  #pragma unroll
  for (int j = 0; j < 8; ++j) h[j] = (_Float16)f[j];
  *(half8*)&At[base] = h;
}

// B plane frag-linear, 64-col-chunk-major (one 64-col chunk = contiguous 32 KB):
// frag f = ((c>>6)*8 + kc)*4 + ((c>>4)&3); half = (f*64 + q*16 + (c&15))*8 + j.
// hcS[c] = 512 + 0.5*|cb_c|^2  (argmin key offset; d' = hcS - dot > 0 always).
__global__ void cb_prep_kernel(const float* __restrict__ cbs,
                               _Float16* __restrict__ Bt,
                               float* __restrict__ hcS) {
  const int tid = threadIdx.x;
  const int R = blockIdx.x * 8 + (tid >> 5);   // layer*4096 + code
  const int layer = R >> 12, c = R & 4095;
  const int t = tid & 31;
  const size_t base = (size_t)R * DIMD + t * 8;
  const float4 v0 = *(const float4*)&cbs[base];
  const float4 v1 = *(const float4*)&cbs[base + 4];
  const float f[8] = {v0.x, v0.y, v0.z, v0.w, v1.x, v1.y, v1.z, v1.w};
  half8 h;
  float s = 0.f;
  #pragma unroll
  for (int j = 0; j < 8; ++j) { h[j] = (_Float16)f[j]; s += f[j] * f[j]; }
  const int kc = t >> 2, q = t & 3;
  _Float16* BtL = Bt + (size_t)layer * KCB * DIMD;
  const int fr = ((c >> 6) * 8 + kc) * 4 + ((c >> 4) & 3);
  *(half8*)&BtL[((size_t)fr * 64 + q * 16 + (c & 15)) * 8] = h;
  #pragma unroll
  for (int off = 16; off > 0; off >>= 1) s += __shfl_down(s, off, 32);
  if (t == 0) hcS[R] = 512.0f + 0.5f * s;
}

// ---------------------------------------------------------------- argmin
// A resident in registers (64 rows x 256 d per wave, gathered once from the
// row-major At); B streamed directly from L2 into registers (no LDS staging,
// no barriers in the main loop). Each wave free-runs over its 64 tiles with
// a p/q half-tile register pipeline; setprio arbitrates the matrix pipe.
__device__ __forceinline__ void upd_keys(const f32x4 (&acc)[4], int tl,
                                         const float* __restrict__ hcs, int ln,
                                         uint32_t* __restrict__ u1,
                                         uint32_t* __restrict__ u2) {
  const float hcv = hcs[tl * 16 + ln];
  #pragma unroll
  for (int rt = 0; rt < 4; ++rt)
    #pragma unroll
    for (int reg = 0; reg < 4; ++reg) {
      const uint32_t k =
          (__float_as_uint(hcv - acc[rt][reg]) & 0xFFFFFFC0u) | (uint32_t)tl;
      const int s = rt * 4 + reg;
      const uint32_t mx = u1[s] > k ? u1[s] : k;
      u1[s] = u1[s] < k ? u1[s] : k;
      u2[s] = u2[s] < mx ? u2[s] : mx;
    }
}

__global__ __launch_bounds__(256, 2) void argmin_kernel(
    const _Float16* __restrict__ At,     // row-major [NTOK][256]
    const _Float16* __restrict__ Bt,     // layer base (chunk-major frag-linear)
    const float* __restrict__ hcS,       // layer base
    uint2* __restrict__ part)            // [NTOK][4] best-2 col indices
{
  __shared__ float hcs[1024];

  const int tid = threadIdx.x;
  const int lane = tid & 63, w = tid >> 6;   // 4 waves
  const int rg   = blockIdx.x & 127;         // stride-128 siblings share rows
  const int colQ = blockIdx.x >> 7;
  const int quad = lane >> 4, ln = lane & 15;

  // stage hcS quarter to LDS (1024 floats)
  *(float4*)&hcs[tid * 4] = *(const float4*)&hcS[colQ * 1024 + tid * 4];

  // upfront A fragment gather from row-major At:
  // a[rt][kc][j] = A[rb16+rt tile, row ln][kc*32 + quad*8 + j]
  const int rb16 = rg * 16 + w * 4;
  half8 a[4][8];
  #pragma unroll
  for (int kc = 0; kc < 8; ++kc)
    #pragma unroll
    for (int rt = 0; rt < 4; ++rt)
      a[rt][kc] = *(const half8*)&At[((size_t)(rb16 + rt) * 16 + ln) * DIMD +
                                     kc * 32 + quad * 8];

  // best-2 keys per element (16 rows/lane): key = trunc6(as_uint(d')) | tile
  uint32_t u1[16], u2[16];
  #pragma unroll
  for (int s = 0; s < 16; ++s) { u1[s] = 0xFFFFFFFFu; u2[s] = 0xFFFFFFFFu; }

  // quarter base: colQ*1024 cols * 256 d = colQ * 262144 halves
  const _Float16* Bq = Bt + (size_t)colQ * 262144 + lane * 8;
  // frag address for (tile t, kc): ((t>>2)*8 + kc)*4 + (t&3), 512 halves each
  #define BFRAG(t, kc) \
    (*(const half8*)&Bq[(size_t)((((t) >> 2) * 8 + (kc)) * 4 + ((t) & 3)) * 512])

  half8 p[4], q[4];
  #pragma unroll
  for (int k = 0; k < 4; ++k) p[k] = BFRAG(0, k);
  #pragma unroll
  for (int k = 0; k < 4; ++k) q[k] = BFRAG(0, 4 + k);

  __syncthreads();   // hcs ready (only barrier in the kernel)

  f32x4 acc[4];
  const f32x4 z = {0.f, 0.f, 0.f, 0.f};

  for (int t = 0; t < 64; ++t) {
    const int tn = (t + 1) & 63;   // wrap keeps addresses valid; t=63 reload is dead
    __builtin_amdgcn_s_setprio(1);
    // consume p (kc 0..3)
    acc[0] = mfma16(a[0][0], p[0], z);
    acc[1] = mfma16(a[1][0], p[0], z);
    acc[2] = mfma16(a[2][0], p[0], z);
    acc[3] = mfma16(a[3][0], p[0], z);
    #pragma unroll
    for (int rt = 0; rt < 4; ++rt) acc[rt] = mfma16(a[rt][1], p[1], acc[rt]);
    #pragma unroll
    for (int rt = 0; rt < 4; ++rt) acc[rt] = mfma16(a[rt][2], p[2], acc[rt]);
    #pragma unroll
    for (int rt = 0; rt < 4; ++rt) acc[rt] = mfma16(a[rt][3], p[3], acc[rt]);
    __builtin_amdgcn_s_setprio(0);
    // refill p <- tile tn half 0 (covered by q-consume + keys)
    #pragma unroll
    for (int k = 0; k < 4; ++k) p[k] = BFRAG(tn, k);
    __builtin_amdgcn_s_setprio(1);
    // consume q (kc 4..7)
    #pragma unroll
    for (int rt = 0; rt < 4; ++rt) acc[rt] = mfma16(a[rt][4], q[0], acc[rt]);
    #pragma unroll
    for (int rt = 0; rt < 4; ++rt) acc[rt] = mfma16(a[rt][5], q[1], acc[rt]);
    #pragma unroll
    for (int rt = 0; rt < 4; ++rt) acc[rt] = mfma16(a[rt][6], q[2], acc[rt]);
    #pragma unroll
    for (int rt = 0; rt < 4; ++rt) acc[rt] = mfma16(a[rt][7], q[3], acc[rt]);
    __builtin_amdgcn_s_setprio(0);
    // refill q <- tile tn half 1 (covered by keys + next p-consume)
    #pragma unroll
    for (int k = 0; k < 4; ++k) q[k] = BFRAG(tn, 4 + k);
    // best-2 key update for tile t
    upd_keys(acc, t, hcs, ln, u1, u2);
  }
  #undef BFRAG

  // flush: reconstruct cols, merge best-2 across the 16 ln lanes, write part
  #pragma unroll
  for (int s = 0; s < 16; ++s) {
    uint32_t k1 = u1[s], k2 = u2[s];
    int c1 = colQ * 1024 + (int)(k1 & 63u) * 16 + ln;
    int c2 = colQ * 1024 + (int)(k2 & 63u) * 16 + ln;
    #pragma unroll
    for (int m = 1; m <= 8; m <<= 1) {
      const uint32_t o1 = (uint32_t)__shfl_xor((int)k1, m, 64);
      const int      oc1 = __shfl_xor(c1, m, 64);
      const uint32_t o2 = (uint32_t)__shfl_xor((int)k2, m, 64);
      const int      oc2 = __shfl_xor(c2, m, 64);
      const bool t1 = k1 <= o1;
      const uint32_t am = t1 ? o1 : k1; const int amc = t1 ? oc1 : c1;
      k1 = t1 ? k1 : o1;                c1 = t1 ? c1 : oc1;
      const bool t2 = k2 <= o2;
      const uint32_t bm = t2 ? k2 : o2; const int bmc = t2 ? c2 : oc2;
      const bool t3 = am <= bm;
      k2 = t3 ? am : bm;                c2 = t3 ? amc : bmc;
    }
    if (ln == 0) {
      const int rt = s >> 2, reg = s & 3;
      const int row = rg * 256 + w * 64 + rt * 16 + quad * 4 + reg;
      part[(size_t)row * 4 + colQ] = make_uint2((uint32_t)c1, (uint32_t)c2);
    }
  }
}

// ------------------------- fused fp64 rescore (8 cands) + STE update + loss
// Residual identity: res_final = x - sum(stv) exactly, so `out` is written
// only at the last layer as out = x - nr (fp diff vs ref sum order ~2e-6).
// Gather pattern dd = k*32 + dg*4: each 8-lane candidate group reads 128 B
// CONTIGUOUS per load (8 cache lines/instr instead of 64).
__global__ void post_kernel(const uint2* __restrict__ part,
                            const float* __restrict__ rsrc,  // x (q=0) or res
                            float* __restrict__ rdst,        // res
                            const float* __restrict__ xin,   // x (last layer)
                            const float* __restrict__ cb,    // layer fp32
                            float* __restrict__ out,
                            _Float16* __restrict__ At,       // row-major
                            float* __restrict__ idxf,
                            float* __restrict__ lossP,       // 256 slots
                            int writeRes, int emit, int writeOut) {
  __shared__ float ls[4];
  const int lane = threadIdx.x & 63;
  const int rsub = threadIdx.x >> 6;
  const int row = blockIdx.x * 4 + rsub;

  // lane-parallel rescore: cand id = lane>>3 (direct per-lane load, no
  // runtime-indexed local array), contiguous chunk = (lane&7)*16 B
  const int cd = lane >> 3, dg = lane & 7;
  const int myc = (int)((const uint32_t*)part)[(size_t)row * 8 + cd];
  const float* rrow = rsrc + (size_t)row * DIMD;
  const float* qrow = cb + (size_t)myc * DIMD;
  double d = 0.0;
  #pragma unroll
  for (int k = 0; k < 8; ++k) {
    const int dd = k * 32 + dg * 4;
    const float4 rv = *(const float4*)&rrow[dd];
    const float4 qv = *(const float4*)&qrow[dd];
    const double t0 = (double)rv.x - (double)qv.x;
    const double t1 = (double)rv.y - (double)qv.y;
    const double t2 = (double)rv.z - (double)qv.z;
    const double t3 = (double)rv.w - (double)qv.w;
    d += t0 * t0 + t1 * t1 + t2 * t2 + t3 * t3;
  }
  #pragma unroll
  for (int m = 1; m <= 4; m <<= 1) d += __shfl_xor(d, m, 64);
  double bd = d; int bc = myc;
  #pragma unroll
  for (int m = 8; m <= 32; m <<= 1) {
    const double od = __shfl_xor(bd, m, 64);
    const int    oc = __shfl_xor(bc, m, 64);
    if (od < bd || (od == bd && oc < bc)) { bd = od; bc = oc; }
  }
  const int win = bc;

  // STE update (reference rounding)
  const size_t base = (size_t)row * DIMD + lane * 4;
  const float4 r4 = *(const float4*)&rsrc[base];
  const float4 q4 = *(const float4*)&cb[(size_t)win * DIMD + lane * 4];
  const float rr[4] = {r4.x, r4.y, r4.z, r4.w};
  const float qq[4] = {q4.x, q4.y, q4.z, q4.w};
  float nr[4];
  float s2 = 0.f;
  #pragma unroll
  for (int j = 0; j < 4; ++j) {
    const float stv = rr[j] + (qq[j] - rr[j]);
    nr[j] = rr[j] - stv;
    const float dl = rr[j] - qq[j];
    s2 += dl * dl;
  }
  if (writeRes)
    *(float4*)&rdst[base] = make_float4(nr[0], nr[1], nr[2], nr[3]);
  if (writeOut) {
    const float4 xv = *(const float4*)&xin[base];
    *(float4*)&out[base] =
        make_float4(xv.x - nr[0], xv.y - nr[1], xv.z - nr[2], xv.w - nr[3]);
  }
  if (emit) {
    // row-major At: fully coalesced half4 store
    half4 h;
    #pragma unroll
    for (int j = 0; j < 4; ++j) h[j] = (_Float16)nr[j];
    *(half4*)&At[base] = h;
  }
  if (lane == 0) idxf[row] = (float)win;

  #pragma unroll
  for (int m = 1; m < 64; m <<= 1) s2 += __shfl_xor(s2, m, 64);
  if (lane == 0) ls[rsub] = s2;
  __syncthreads();
  if (threadIdx.x == 0) {
    const float tot = ls[0] + ls[1] + ls[2] + ls[3];
    atomicAdd(&lossP[blockIdx.x & 255],
              tot * (1.0f / (float)((size_t)NTOK * DIMD)));
  }
}

// sum 4 x 256 loss partials -> losses[4]
__global__ void finalize_kernel(const float* __restrict__ lossP,
                                float* __restrict__ losses) {
  const int w = threadIdx.x >> 6, lane = threadIdx.x & 63;
  float s = lossP[w * 256 + lane] + lossP[w * 256 + 64 + lane] +
            lossP[w * 256 + 128 + lane] + lossP[w * 256 + 192 + lane];
  #pragma unroll
  for (int m = 1; m < 64; m <<= 1) s += __shfl_xor(s, m, 64);
  if (lane == 0) losses[w] = s;
}

// ---------------------------------------------------------------- launch
extern "C" void kernel_launch(void* const* d_in, const int* in_sizes, int n_in,
                              void* d_out, int out_size, void* d_ws, size_t ws_size,
                              hipStream_t stream) {
  const float* x   = (const float*)d_in[0];   // [8,4096,256]
  const float* cbs = (const float*)d_in[1];   // [4,4096,256]

  float* out    = (float*)d_out;
  float* idxf   = out + (size_t)NTOK * DIMD;
  float* losses = idxf + (size_t)NQ * NTOK;

  char* wsp = (char*)d_ws;
  float* res = (float*)wsp;                    wsp += (size_t)NTOK * DIMD * 4;      // 32 MB
  _Float16* At = (_Float16*)wsp;               wsp += (size_t)NTOK * DIMD * 2;      // 16 MB
  _Float16* Bt = (_Float16*)wsp;               wsp += (size_t)NQ * KCB * DIMD * 2;  //  8 MB
  float* hcS = (float*)wsp;                    wsp += (size_t)NQ * KCB * 4;
  uint2* part = (uint2*)wsp;                   wsp += (size_t)NTOK * 4 * 8;
  float* lossP = (float*)wsp;                  wsp += (size_t)NQ * 256 * 4;

  hipMemsetAsync(lossP, 0, NQ * 256 * sizeof(float), stream);
  cb_prep_kernel<<<NQ * KCB / 8, 256, 0, stream>>>(cbs, Bt, hcS);
  init_kernel<<<NTOK / 8, 256, 0, stream>>>(x, At);

  for (int q = 0; q < NQ; ++q) {
    const float* cb = cbs + (size_t)q * KCB * DIMD;
    argmin_kernel<<<512, 256, 0, stream>>>(At, Bt + (size_t)q * KCB * DIMD,
                                           hcS + (size_t)q * KCB, part);
    const int last = (q == NQ - 1);
    post_kernel<<<NTOK / 4, 256, 0, stream>>>(
        part, q == 0 ? x : res, res, x, cb, out, At,
        idxf + (size_t)q * NTOK, lossP + (size_t)q * 256,
        /*writeRes=*/!last, /*emit=*/!last, /*writeOut=*/last);
  }
  finalize_kernel<<<1, 256, 0, stream>>>(lossP, losses);
}